// Round 9
// baseline (117.399 us; speedup 1.0000x reference)
//
#include <hip/hip_runtime.h>
#include <math.h>
#include <float.h>
#include <utility>

#define B_ 2
#define NQ 1024
#define NO 1024
#define LAT 128
#define NHEADS 4
#define RADIUS_ 0.5f
#define LN_EPS_ 1e-5f
#define CAP 256          // items buffered per wave pass
#define PPAD 264         // p-row stride (heads on banks 0/8/16/24)

__device__ __forceinline__ float selh(int h, float a, float b, float c, float d) {
  return h == 0 ? a : (h == 1 ? b : (h == 2 ? c : d));
}
__device__ __forceinline__ float rdlane(float v, int l) {
  return __int_as_float(__builtin_amdgcn_readlane(__float_as_int(v), l));
}

// ---------------- prep: v = LayerNorm(h_obs) @ Wv + bv, 4 rows/block -------
__global__ __launch_bounds__(256) void gano_prep_kernel(
    const float* __restrict__ h_obs, const float* __restrict__ ln_g,
    const float* __restrict__ ln_b, const float* __restrict__ Wv,
    const float* __restrict__ bv, float* __restrict__ v_out)
{
  const int tid = threadIdx.x;
  const int j = tid & 127;
  const int half = tid >> 7;
  const int wave = tid >> 6;
  const int lane = tid & 63;
  const int r0 = blockIdx.x * 4 + half * 2;

  __shared__ float s_redA[2][4];
  __shared__ float s_redB[2][4];
  __shared__ __align__(16) float s_hn[4][LAT];

  const float x0 = h_obs[(size_t)r0 * LAT + j];
  const float x1 = h_obs[(size_t)(r0 + 1) * LAT + j];
  float s0 = x0, s1 = x1;
  #pragma unroll
  for (int off = 32; off >= 1; off >>= 1) {
    s0 += __shfl_down(s0, off);
    s1 += __shfl_down(s1, off);
  }
  if (lane == 0) { s_redA[0][wave] = s0; s_redA[1][wave] = s1; }
  __syncthreads();
  const float mu0 = (s_redA[0][half * 2] + s_redA[0][half * 2 + 1]) * (1.0f / LAT);
  const float mu1 = (s_redA[1][half * 2] + s_redA[1][half * 2 + 1]) * (1.0f / LAT);
  const float d0 = x0 - mu0, d1 = x1 - mu1;
  float q0 = d0 * d0, q1 = d1 * d1;
  #pragma unroll
  for (int off = 32; off >= 1; off >>= 1) {
    q0 += __shfl_down(q0, off);
    q1 += __shfl_down(q1, off);
  }
  if (lane == 0) { s_redB[0][wave] = q0; s_redB[1][wave] = q1; }
  __syncthreads();
  const float var0 = (s_redB[0][half * 2] + s_redB[0][half * 2 + 1]) * (1.0f / LAT);
  const float var1 = (s_redB[1][half * 2] + s_redB[1][half * 2 + 1]) * (1.0f / LAT);
  const float g = ln_g[j], be = ln_b[j];
  s_hn[half * 2 + 0][j] = d0 * rsqrtf(var0 + LN_EPS_) * g + be;
  s_hn[half * 2 + 1][j] = d1 * rsqrtf(var1 + LN_EPS_) * g + be;
  __syncthreads();

  float a0 = 0.0f, a1 = 0.0f;
  const float4* h0 = (const float4*)s_hn[half * 2 + 0];
  const float4* h1 = (const float4*)s_hn[half * 2 + 1];
  #pragma unroll 4
  for (int k4 = 0; k4 < LAT / 4; ++k4) {
    const float4 u0 = h0[k4];
    const float4 u1 = h1[k4];
    const float w0 = Wv[(k4 * 4 + 0) * LAT + j];
    const float w1 = Wv[(k4 * 4 + 1) * LAT + j];
    const float w2 = Wv[(k4 * 4 + 2) * LAT + j];
    const float w3 = Wv[(k4 * 4 + 3) * LAT + j];
    a0 = fmaf(u0.x, w0, a0); a0 = fmaf(u0.y, w1, a0);
    a0 = fmaf(u0.z, w2, a0); a0 = fmaf(u0.w, w3, a0);
    a1 = fmaf(u1.x, w0, a1); a1 = fmaf(u1.y, w1, a1);
    a1 = fmaf(u1.z, w2, a1); a1 = fmaf(u1.w, w3, a1);
  }
  const float bvj = bv[j];
  v_out[(size_t)(r0 + 0) * LAT + j] = a0 + bvj;
  v_out[(size_t)(r0 + 1) * LAT + j] = a1 + bvj;
}

// ---------------- main: wave = half query; weights register-resident -------
__global__ __launch_bounds__(256, 4) void gano_main_kernel(
    const float* __restrict__ pos_obs, const float* __restrict__ pos_query,
    const int* __restrict__ obs_mask,
    const float* __restrict__ W1, const float* __restrict__ b1,
    const float* __restrict__ W2, const float* __restrict__ b2,
    const float* __restrict__ v, float* __restrict__ out)
{
  __shared__ __align__(16) float4 s_list[4][CAP];        // 16 KB
  __shared__ int   s_idx[4][CAP];                        // 4 KB
  __shared__ __align__(16) float s_p[4][NHEADS * PPAD];  // 16.5 KB
  __shared__ __align__(16) float s_acc[4][LAT];          // 2 KB
  __shared__ float s_mz[4][2][NHEADS];
  __shared__ int   s_cnt4[4];

  const int tid = threadIdx.x;
  const int wave = tid >> 6, lane = tid & 63;
  const int qg = blockIdx.x * 2 + (wave >> 1);   // global query
  const int hhalf = wave & 1;                    // obs half for this wave
  const int b = qg >> 10;

  const float qx = pos_query[(size_t)qg * 3 + 0];
  const float qy = pos_query[(size_t)qg * 3 + 1];
  const float qz = pos_query[(size_t)qg * 3 + 2];

  // ---- register-resident derived weights + Q row (lane holds j=lane, j=64+lane)
  float wA0, wA1, wA2, wA3, wA4, wA5, wA6, wA7, qA;
  float wB0, wB1, wB2, wB3, wB4, wB5, wB6, wB7, qB;
  {
    const int jj = lane;
    const float r0 = W1[0 * LAT + jj], r1 = W1[1 * LAT + jj], r2 = W1[2 * LAT + jj];
    const float r3 = W1[3 * LAT + jj], r4 = W1[4 * LAT + jj], r5 = W1[5 * LAT + jj];
    const float r6 = W1[6 * LAT + jj], r7 = W1[7 * LAT + jj], r8 = W1[8 * LAT + jj];
    const float r9 = W1[9 * LAT + jj];
    wA0 = r3 - r6; wA1 = r4 - r7; wA2 = r5 - r8; wA3 = r9;
    const float4 w2r = *(const float4*)&W2[jj * NHEADS];
    wA4 = w2r.x; wA5 = w2r.y; wA6 = w2r.z; wA7 = w2r.w;
    qA = b1[jj] + qx * (r0 + r6) + qy * (r1 + r7) + qz * (r2 + r8);
  }
  {
    const int jj = 64 + lane;
    const float r0 = W1[0 * LAT + jj], r1 = W1[1 * LAT + jj], r2 = W1[2 * LAT + jj];
    const float r3 = W1[3 * LAT + jj], r4 = W1[4 * LAT + jj], r5 = W1[5 * LAT + jj];
    const float r6 = W1[6 * LAT + jj], r7 = W1[7 * LAT + jj], r8 = W1[8 * LAT + jj];
    const float r9 = W1[9 * LAT + jj];
    wB0 = r3 - r6; wB1 = r4 - r7; wB2 = r5 - r8; wB3 = r9;
    const float4 w2r = *(const float4*)&W2[jj * NHEADS];
    wB4 = w2r.x; wB5 = w2r.y; wB6 = w2r.z; wB7 = w2r.w;
    qB = b1[jj] + qx * (r0 + r6) + qy * (r1 + r7) + qz * (r2 + r8);
  }

  const float* pob = pos_obs + (size_t)b * NO * 3;
  const int*   om  = obs_mask + (size_t)b * NO;
  const float b20 = b2[0], b21 = b2[1], b22 = b2[2], b23 = b2[3];
  const int c0 = lane << 1;
  const int hh = lane >> 4;
  const float* vb = v + (size_t)b * NO * LAT + c0;

  float m0 = -FLT_MAX, m1 = -FLT_MAX, m2 = -FLT_MAX, m3 = -FLT_MAX;
  float z0 = 0.f, z1 = 0.f, z2 = 0.f, z3 = 0.f;
  float ax = 0.f, ay = 0.f;

  float4* listw = s_list[wave];
  int*    idxw  = s_idx[wave];
  float*  pw    = s_p[wave];
  int base = 0, nvtot = 0;

  // ---- flash pass over <=CAP buffered items (wave-private, no barriers) ----
  auto flash = [&](auto nsc) {
    constexpr int NS = decltype(nsc)::value;
    const int cnt = base;
    float4 C[NS];
    bool act[NS];
    #pragma unroll
    for (int r = 0; r < NS; ++r) {
      const int s = r * 64 + lane;
      act[r] = s < cnt;
      C[r] = listw[act[r] ? s : (cnt - 1)];
    }
    float L[NS][NHEADS];
    #pragma unroll
    for (int r = 0; r < NS; ++r) {
      L[r][0] = b20; L[r][1] = b21; L[r][2] = b22; L[r][3] = b23;
    }

    // MLP over j: weights broadcast lane->SGPR via readlane (no memory!)
    auto half_loop = [&](float hw0, float hw1, float hw2, float hw3,
                         float hw4, float hw5, float hw6, float hw7, float hq) {
      #pragma unroll 4
      for (int l = 0; l < 64; ++l) {
        const float qj = rdlane(hq, l);
        const float cw0 = rdlane(hw0, l), cw1 = rdlane(hw1, l);
        const float cw2 = rdlane(hw2, l), cw3 = rdlane(hw3, l);
        const float u0 = rdlane(hw4, l), u1 = rdlane(hw5, l);
        const float u2 = rdlane(hw6, l), u3 = rdlane(hw7, l);
        #pragma unroll
        for (int r = 0; r < NS; ++r) {
          float gg = fmaf(cw0, C[r].x, qj);
          gg = fmaf(cw1, C[r].y, gg);
          gg = fmaf(cw2, C[r].z, gg);
          gg = fmaf(cw3, C[r].w, gg);
          gg = fmaxf(gg, 0.0f);
          L[r][0] = fmaf(gg, u0, L[r][0]);
          L[r][1] = fmaf(gg, u1, L[r][1]);
          L[r][2] = fmaf(gg, u2, L[r][2]);
          L[r][3] = fmaf(gg, u3, L[r][3]);
        }
      }
    };
    half_loop(wA0, wA1, wA2, wA3, wA4, wA5, wA6, wA7, qA);
    half_loop(wB0, wB1, wB2, wB3, wB4, wB5, wB6, wB7, qB);

    #pragma unroll
    for (int r = 0; r < NS; ++r)
      if (!act[r]) { L[r][0] = L[r][1] = L[r][2] = L[r][3] = -FLT_MAX; }

    float x0 = L[0][0], x1 = L[0][1], x2 = L[0][2], x3 = L[0][3];
    #pragma unroll
    for (int r = 1; r < NS; ++r) {
      x0 = fmaxf(x0, L[r][0]); x1 = fmaxf(x1, L[r][1]);
      x2 = fmaxf(x2, L[r][2]); x3 = fmaxf(x3, L[r][3]);
    }
    #pragma unroll
    for (int off = 1; off < 64; off <<= 1) {
      x0 = fmaxf(x0, __shfl_xor(x0, off));
      x1 = fmaxf(x1, __shfl_xor(x1, off));
      x2 = fmaxf(x2, __shfl_xor(x2, off));
      x3 = fmaxf(x3, __shfl_xor(x3, off));
    }
    const float nm0 = fmaxf(m0, x0), nm1 = fmaxf(m1, x1);
    const float nm2 = fmaxf(m2, x2), nm3 = fmaxf(m3, x3);
    const float sc0 = __expf(m0 - nm0), sc1 = __expf(m1 - nm1);
    const float sc2 = __expf(m2 - nm2), sc3 = __expf(m3 - nm3);
    m0 = nm0; m1 = nm1; m2 = nm2; m3 = nm3;

    float pz0 = 0.f, pz1 = 0.f, pz2 = 0.f, pz3 = 0.f;
    #pragma unroll
    for (int r = 0; r < NS; ++r) {
      const float p0 = __expf(L[r][0] - nm0);
      const float p1 = __expf(L[r][1] - nm1);
      const float p2 = __expf(L[r][2] - nm2);
      const float p3 = __expf(L[r][3] - nm3);
      const int s = r * 64 + lane;
      pw[0 * PPAD + s] = p0;
      pw[1 * PPAD + s] = p1;
      pw[2 * PPAD + s] = p2;
      pw[3 * PPAD + s] = p3;
      pz0 += p0; pz1 += p1; pz2 += p2; pz3 += p3;
    }
    #pragma unroll
    for (int off = 1; off < 64; off <<= 1) {
      pz0 += __shfl_xor(pz0, off);
      pz1 += __shfl_xor(pz1, off);
      pz2 += __shfl_xor(pz2, off);
      pz3 += __shfl_xor(pz3, off);
    }
    z0 = z0 * sc0 + pz0;
    z1 = z1 * sc1 + pz1;
    z2 = z2 * sc2 + pz2;
    z3 = z3 * sc3 + pz3;

    const float sch = selh(hh, sc0, sc1, sc2, sc3);
    ax *= sch; ay *= sch;
    const float* pr = pw + hh * PPAD;
    #pragma unroll 2
    for (int it = 0; it < cnt; it += 4) {
      const float4 pq = *(const float4*)&pr[it];
      const int4 iq = *(const int4*)&idxw[it];
      const float2 v0 = *(const float2*)(vb + (size_t)(iq.x & (NO - 1)) * LAT);
      const float2 v1 = *(const float2*)(vb + (size_t)(iq.y & (NO - 1)) * LAT);
      const float2 v2 = *(const float2*)(vb + (size_t)(iq.z & (NO - 1)) * LAT);
      const float2 v3 = *(const float2*)(vb + (size_t)(iq.w & (NO - 1)) * LAT);
      ax = fmaf(pq.x, v0.x, ax); ay = fmaf(pq.x, v0.y, ay);
      ax = fmaf(pq.y, v1.x, ax); ay = fmaf(pq.y, v1.y, ay);
      ax = fmaf(pq.z, v2.x, ax); ay = fmaf(pq.z, v2.y, ay);
      ax = fmaf(pq.w, v3.x, ax); ay = fmaf(pq.w, v3.y, ay);
    }
  };
  auto dispatch = [&]() {
    const int ns = (base + 63) >> 6;
    if (ns == 4)      flash(std::integral_constant<int, 4>{});
    else if (ns == 3) flash(std::integral_constant<int, 3>{});
    else if (ns == 2) flash(std::integral_constant<int, 2>{});
    else              flash(std::integral_constant<int, 1>{});
  };

  // ---- compaction of this wave's obs half (512 obs, 8 rounds) ----
  for (int rd = 0; rd < 8; ++rd) {
    const int o = (hhalf << 9) + (rd << 6) + lane;
    const float ox = pob[o * 3 + 0], oy = pob[o * 3 + 1], oz = pob[o * 3 + 2];
    const float rx = qx - ox, ry = qy - oy, rz = qz - oz;
    const float dist = sqrtf(rx * rx + ry * ry + rz * rz);
    const int ok = (om[o] != 0) && (dist <= RADIUS_);
    const unsigned long long bal = __ballot(ok);
    const int cnt = __popcll(bal);
    if (base + cnt > CAP) { dispatch(); base = 0; }
    if (ok) {
      const int pos = base + __popcll(bal & ((1ull << lane) - 1ull));
      listw[pos] = make_float4(ox, oy, oz, dist);
      idxw[pos] = o;
    }
    base += cnt;
    nvtot += cnt;
  }
  if (base > 0) dispatch();

  // ---- publish per-wave state, merge the two halves of each query ----
  if (lane == 0) {
    s_mz[wave][0][0] = m0; s_mz[wave][0][1] = m1;
    s_mz[wave][0][2] = m2; s_mz[wave][0][3] = m3;
    s_mz[wave][1][0] = z0; s_mz[wave][1][1] = z1;
    s_mz[wave][1][2] = z2; s_mz[wave][1][3] = z3;
    s_cnt4[wave] = nvtot;
  }
  s_acc[wave][c0] = ax;
  s_acc[wave][c0 + 1] = ay;
  __syncthreads();

  {
    const int pair = tid >> 7;            // 0: query qg0, 1: query qg1
    const int col = tid & 127;
    const int wA = pair * 2, wB = wA + 1;
    const int h = col >> 5;
    const int qout = blockIdx.x * 2 + pair;
    const int ct = s_cnt4[wA] + s_cnt4[wB];
    const float mA = s_mz[wA][0][h], mB = s_mz[wB][0][h];
    const float M = fmaxf(mA, mB);
    const float eA = __expf(mA - M), eB = __expf(mB - M);
    const float num = eA * s_acc[wA][col] + eB * s_acc[wB][col];
    const float den = eA * s_mz[wA][1][h] + eB * s_mz[wB][1][h];
    const float r = (ct > 0) ? (num / den) : 0.0f;
    out[(size_t)qout * LAT + col] = r;
  }
}

extern "C" void kernel_launch(void* const* d_in, const int* in_sizes, int n_in,
                              void* d_out, int out_size, void* d_ws, size_t ws_size,
                              hipStream_t stream) {
  const float* h_obs     = (const float*)d_in[0];
  const float* pos_obs   = (const float*)d_in[1];
  const float* pos_query = (const float*)d_in[2];
  const int*   obs_mask  = (const int*)d_in[3];
  const float* W1        = (const float*)d_in[4];
  const float* b1        = (const float*)d_in[5];
  const float* W2        = (const float*)d_in[6];
  const float* b2        = (const float*)d_in[7];
  const float* ln_g      = (const float*)d_in[8];
  const float* ln_b      = (const float*)d_in[9];
  const float* Wv        = (const float*)d_in[10];
  const float* bv        = (const float*)d_in[11];
  float* outp = (float*)d_out;
  float* v    = (float*)d_ws;   // 1 MB

  gano_prep_kernel<<<(B_ * NO) / 4, 256, 0, stream>>>(h_obs, ln_g, ln_b, Wv, bv, v);
  gano_main_kernel<<<B_ * NQ / 2, 256, 0, stream>>>(pos_obs, pos_query, obs_mask,
                                                    W1, b1, W2, b2, v, outp);
}

// Round 10
// 63.462 us; speedup vs baseline: 1.8499x; 1.8499x over previous
//
#include <hip/hip_runtime.h>
#include <math.h>
#include <float.h>

#define B_ 2
#define NQ 1024
#define NO 1024
#define LAT 128
#define NHEADS 4
#define RADIUS_ 0.5f
#define LN_EPS_ 1e-5f
#define CAP 1024
#define PASS 192         // 3 slots x 64 lanes per flash pass
#define PPAD 196         // p row stride

__device__ __forceinline__ float selh(int h, float a, float b, float c, float d) {
  return h == 0 ? a : (h == 1 ? b : (h == 2 ? c : d));
}
__device__ __forceinline__ float rdl(float v, int l) {
  return __int_as_float(__builtin_amdgcn_readlane(__float_as_int(v), l));
}

// ---------------- prep: v = LayerNorm(h_obs) @ Wv + bv, 4 rows/block -------
__global__ __launch_bounds__(256) void gano_prep_kernel(
    const float* __restrict__ h_obs, const float* __restrict__ ln_g,
    const float* __restrict__ ln_b, const float* __restrict__ Wv,
    const float* __restrict__ bv, float* __restrict__ v_out)
{
  const int tid = threadIdx.x;
  const int j = tid & 127;
  const int half = tid >> 7;
  const int wave = tid >> 6;
  const int lane = tid & 63;
  const int r0 = blockIdx.x * 4 + half * 2;

  __shared__ float s_redA[2][4];
  __shared__ float s_redB[2][4];
  __shared__ __align__(16) float s_hn[4][LAT];

  const float x0 = h_obs[(size_t)r0 * LAT + j];
  const float x1 = h_obs[(size_t)(r0 + 1) * LAT + j];
  float s0 = x0, s1 = x1;
  #pragma unroll
  for (int off = 32; off >= 1; off >>= 1) {
    s0 += __shfl_down(s0, off);
    s1 += __shfl_down(s1, off);
  }
  if (lane == 0) { s_redA[0][wave] = s0; s_redA[1][wave] = s1; }
  __syncthreads();
  const float mu0 = (s_redA[0][half * 2] + s_redA[0][half * 2 + 1]) * (1.0f / LAT);
  const float mu1 = (s_redA[1][half * 2] + s_redA[1][half * 2 + 1]) * (1.0f / LAT);
  const float d0 = x0 - mu0, d1 = x1 - mu1;
  float q0 = d0 * d0, q1 = d1 * d1;
  #pragma unroll
  for (int off = 32; off >= 1; off >>= 1) {
    q0 += __shfl_down(q0, off);
    q1 += __shfl_down(q1, off);
  }
  if (lane == 0) { s_redB[0][wave] = q0; s_redB[1][wave] = q1; }
  __syncthreads();
  const float var0 = (s_redB[0][half * 2] + s_redB[0][half * 2 + 1]) * (1.0f / LAT);
  const float var1 = (s_redB[1][half * 2] + s_redB[1][half * 2 + 1]) * (1.0f / LAT);
  const float g = ln_g[j], be = ln_b[j];
  s_hn[half * 2 + 0][j] = d0 * rsqrtf(var0 + LN_EPS_) * g + be;
  s_hn[half * 2 + 1][j] = d1 * rsqrtf(var1 + LN_EPS_) * g + be;
  __syncthreads();

  float a0 = 0.0f, a1 = 0.0f;
  const float4* h0 = (const float4*)s_hn[half * 2 + 0];
  const float4* h1 = (const float4*)s_hn[half * 2 + 1];
  #pragma unroll 4
  for (int k4 = 0; k4 < LAT / 4; ++k4) {
    const float4 u0 = h0[k4];
    const float4 u1 = h1[k4];
    const float w0 = Wv[(k4 * 4 + 0) * LAT + j];
    const float w1 = Wv[(k4 * 4 + 1) * LAT + j];
    const float w2 = Wv[(k4 * 4 + 2) * LAT + j];
    const float w3 = Wv[(k4 * 4 + 3) * LAT + j];
    a0 = fmaf(u0.x, w0, a0); a0 = fmaf(u0.y, w1, a0);
    a0 = fmaf(u0.z, w2, a0); a0 = fmaf(u0.w, w3, a0);
    a1 = fmaf(u1.x, w0, a1); a1 = fmaf(u1.y, w1, a1);
    a1 = fmaf(u1.z, w2, a1); a1 = fmaf(u1.w, w3, a1);
  }
  const float bvj = bv[j];
  v_out[(size_t)(r0 + 0) * LAT + j] = a0 + bvj;
  v_out[(size_t)(r0 + 1) * LAT + j] = a1 + bvj;
}

// ---------------- main: one wave = one query; weights in registers --------
__global__ __launch_bounds__(64, 4) void gano_main_kernel(
    const float* __restrict__ pos_obs, const float* __restrict__ pos_query,
    const int* __restrict__ obs_mask,
    const float* __restrict__ W1, const float* __restrict__ b1,
    const float* __restrict__ W2, const float* __restrict__ b2,
    const float* __restrict__ v, float* __restrict__ out)
{
  __shared__ int   s_idx[CAP];                       // 4 KB
  __shared__ float s_dist[CAP];                      // 4 KB
  __shared__ __align__(16) float s_p[NHEADS][PPAD];  // 3.1 KB

  const int lane = threadIdx.x;
  const int qg = blockIdx.x;
  const int b = qg >> 10;

  const float qx = pos_query[(size_t)qg * 3 + 0];
  const float qy = pos_query[(size_t)qg * 3 + 1];
  const float qz = pos_query[(size_t)qg * 3 + 2];

  // ---- register-resident weights: lane holds rows j=lane and j=64+lane ----
  float wA0, wA1, wA2, wA3, wA4, wA5, wA6, wA7, qA;
  float wB0, wB1, wB2, wB3, wB4, wB5, wB6, wB7, qB;
  {
    const int jj = lane;
    const float r0 = W1[0 * LAT + jj], r1 = W1[1 * LAT + jj], r2 = W1[2 * LAT + jj];
    const float r3 = W1[3 * LAT + jj], r4 = W1[4 * LAT + jj], r5 = W1[5 * LAT + jj];
    const float r6 = W1[6 * LAT + jj], r7 = W1[7 * LAT + jj], r8 = W1[8 * LAT + jj];
    wA0 = r3 - r6; wA1 = r4 - r7; wA2 = r5 - r8; wA3 = W1[9 * LAT + jj];
    const float4 w2r = *(const float4*)&W2[jj * NHEADS];
    wA4 = w2r.x; wA5 = w2r.y; wA6 = w2r.z; wA7 = w2r.w;
    qA = b1[jj] + qx * (r0 + r6) + qy * (r1 + r7) + qz * (r2 + r8);
  }
  {
    const int jj = 64 + lane;
    const float r0 = W1[0 * LAT + jj], r1 = W1[1 * LAT + jj], r2 = W1[2 * LAT + jj];
    const float r3 = W1[3 * LAT + jj], r4 = W1[4 * LAT + jj], r5 = W1[5 * LAT + jj];
    const float r6 = W1[6 * LAT + jj], r7 = W1[7 * LAT + jj], r8 = W1[8 * LAT + jj];
    wB0 = r3 - r6; wB1 = r4 - r7; wB2 = r5 - r8; wB3 = W1[9 * LAT + jj];
    const float4 w2r = *(const float4*)&W2[jj * NHEADS];
    wB4 = w2r.x; wB5 = w2r.y; wB6 = w2r.z; wB7 = w2r.w;
    qB = b1[jj] + qx * (r0 + r6) + qy * (r1 + r7) + qz * (r2 + r8);
  }

  const float* pob = pos_obs + (size_t)b * NO * 3;
  const int*   om  = obs_mask + (size_t)b * NO;
  const float b20 = b2[0], b21 = b2[1], b22 = b2[2], b23 = b2[3];
  const int c0 = lane << 1;
  const int hh = lane >> 4;
  const float* vb = v + (size_t)b * NO * LAT + c0;

  // ---- compaction: whole obs list into LDS (wave-private, no barriers) ----
  int base = 0;
  for (int rd = 0; rd < 16; ++rd) {
    const int o = (rd << 6) + lane;
    const float ox = pob[o * 3 + 0], oy = pob[o * 3 + 1], oz = pob[o * 3 + 2];
    const float rx = qx - ox, ry = qy - oy, rz = qz - oz;
    const float dist = sqrtf(rx * rx + ry * ry + rz * rz);
    const int ok = (om[o] != 0) && (dist <= RADIUS_);
    const unsigned long long bal = __ballot(ok);
    if (ok) {
      const int pos = base + __popcll(bal & ((1ull << lane) - 1ull));
      s_idx[pos] = o;
      s_dist[pos] = dist;
    }
    base += __popcll(bal);
  }
  const int Nv = base;

  float m0 = -FLT_MAX, m1 = -FLT_MAX, m2 = -FLT_MAX, m3 = -FLT_MAX;
  float z0 = 0.f, z1 = 0.f, z2 = 0.f, z3 = 0.f;
  float ax = 0.f, ay = 0.f;

  // ---- flash passes of 192 items (3 slots/lane), single code path ----
  for (int pbase = 0; pbase < Nv; pbase += PASS) {
    const int cnt = min(PASS, Nv - pbase);
    // load 3 slots (idx+dist from LDS, coords from L2)
    const int t0s = pbase + lane, t1s = pbase + 64 + lane, t2s = pbase + 128 + lane;
    const bool a0v = t0s < Nv, a1v = t1s < Nv, a2v = t2s < Nv;
    const int cs0 = a0v ? t0s : Nv - 1;
    const int cs1 = a1v ? t1s : Nv - 1;
    const int cs2 = a2v ? t2s : Nv - 1;
    const int i0 = s_idx[cs0], i1 = s_idx[cs1], i2 = s_idx[cs2];
    const float d0 = s_dist[cs0], d1 = s_dist[cs1], d2 = s_dist[cs2];
    const float ox0 = pob[i0 * 3 + 0], oy0 = pob[i0 * 3 + 1], oz0 = pob[i0 * 3 + 2];
    const float ox1 = pob[i1 * 3 + 0], oy1 = pob[i1 * 3 + 1], oz1 = pob[i1 * 3 + 2];
    const float ox2 = pob[i2 * 3 + 0], oy2 = pob[i2 * 3 + 1], oz2 = pob[i2 * 3 + 2];

    float L00 = b20, L01 = b21, L02 = b22, L03 = b23;
    float L10 = b20, L11 = b21, L12 = b22, L13 = b23;
    float L20 = b20, L21 = b21, L22 = b22, L23 = b23;

    for (int l = 0; l < 64; ++l) {
      // j = l (A half)
      {
        const float qj = rdl(qA, l);
        const float c0w = rdl(wA0, l), c1w = rdl(wA1, l);
        const float c2w = rdl(wA2, l), c3w = rdl(wA3, l);
        const float u0 = rdl(wA4, l), u1 = rdl(wA5, l);
        const float u2 = rdl(wA6, l), u3 = rdl(wA7, l);
        float g0 = fmaf(c0w, ox0, qj); g0 = fmaf(c1w, oy0, g0);
        g0 = fmaf(c2w, oz0, g0); g0 = fmaf(c3w, d0, g0); g0 = fmaxf(g0, 0.f);
        float g1 = fmaf(c0w, ox1, qj); g1 = fmaf(c1w, oy1, g1);
        g1 = fmaf(c2w, oz1, g1); g1 = fmaf(c3w, d1, g1); g1 = fmaxf(g1, 0.f);
        float g2 = fmaf(c0w, ox2, qj); g2 = fmaf(c1w, oy2, g2);
        g2 = fmaf(c2w, oz2, g2); g2 = fmaf(c3w, d2, g2); g2 = fmaxf(g2, 0.f);
        L00 = fmaf(g0, u0, L00); L01 = fmaf(g0, u1, L01);
        L02 = fmaf(g0, u2, L02); L03 = fmaf(g0, u3, L03);
        L10 = fmaf(g1, u0, L10); L11 = fmaf(g1, u1, L11);
        L12 = fmaf(g1, u2, L12); L13 = fmaf(g1, u3, L13);
        L20 = fmaf(g2, u0, L20); L21 = fmaf(g2, u1, L21);
        L22 = fmaf(g2, u2, L22); L23 = fmaf(g2, u3, L23);
      }
      // j = 64 + l (B half)
      {
        const float qj = rdl(qB, l);
        const float c0w = rdl(wB0, l), c1w = rdl(wB1, l);
        const float c2w = rdl(wB2, l), c3w = rdl(wB3, l);
        const float u0 = rdl(wB4, l), u1 = rdl(wB5, l);
        const float u2 = rdl(wB6, l), u3 = rdl(wB7, l);
        float g0 = fmaf(c0w, ox0, qj); g0 = fmaf(c1w, oy0, g0);
        g0 = fmaf(c2w, oz0, g0); g0 = fmaf(c3w, d0, g0); g0 = fmaxf(g0, 0.f);
        float g1 = fmaf(c0w, ox1, qj); g1 = fmaf(c1w, oy1, g1);
        g1 = fmaf(c2w, oz1, g1); g1 = fmaf(c3w, d1, g1); g1 = fmaxf(g1, 0.f);
        float g2 = fmaf(c0w, ox2, qj); g2 = fmaf(c1w, oy2, g2);
        g2 = fmaf(c2w, oz2, g2); g2 = fmaf(c3w, d2, g2); g2 = fmaxf(g2, 0.f);
        L00 = fmaf(g0, u0, L00); L01 = fmaf(g0, u1, L01);
        L02 = fmaf(g0, u2, L02); L03 = fmaf(g0, u3, L03);
        L10 = fmaf(g1, u0, L10); L11 = fmaf(g1, u1, L11);
        L12 = fmaf(g1, u2, L12); L13 = fmaf(g1, u3, L13);
        L20 = fmaf(g2, u0, L20); L21 = fmaf(g2, u1, L21);
        L22 = fmaf(g2, u2, L22); L23 = fmaf(g2, u3, L23);
      }
    }

    if (!a0v) { L00 = L01 = L02 = L03 = -FLT_MAX; }
    if (!a1v) { L10 = L11 = L12 = L13 = -FLT_MAX; }
    if (!a2v) { L20 = L21 = L22 = L23 = -FLT_MAX; }

    // pass max per head
    float x0 = fmaxf(fmaxf(L00, L10), L20);
    float x1 = fmaxf(fmaxf(L01, L11), L21);
    float x2 = fmaxf(fmaxf(L02, L12), L22);
    float x3 = fmaxf(fmaxf(L03, L13), L23);
    #pragma unroll
    for (int off = 1; off < 64; off <<= 1) {
      x0 = fmaxf(x0, __shfl_xor(x0, off));
      x1 = fmaxf(x1, __shfl_xor(x1, off));
      x2 = fmaxf(x2, __shfl_xor(x2, off));
      x3 = fmaxf(x3, __shfl_xor(x3, off));
    }
    const float nm0 = fmaxf(m0, x0), nm1 = fmaxf(m1, x1);
    const float nm2 = fmaxf(m2, x2), nm3 = fmaxf(m3, x3);
    const float sc0 = __expf(m0 - nm0), sc1 = __expf(m1 - nm1);
    const float sc2 = __expf(m2 - nm2), sc3 = __expf(m3 - nm3);
    m0 = nm0; m1 = nm1; m2 = nm2; m3 = nm3;

    const float p00 = __expf(L00 - nm0), p01 = __expf(L01 - nm1);
    const float p02 = __expf(L02 - nm2), p03 = __expf(L03 - nm3);
    const float p10 = __expf(L10 - nm0), p11 = __expf(L11 - nm1);
    const float p12 = __expf(L12 - nm2), p13 = __expf(L13 - nm3);
    const float p20 = __expf(L20 - nm0), p21 = __expf(L21 - nm1);
    const float p22 = __expf(L22 - nm2), p23 = __expf(L23 - nm3);
    s_p[0][lane] = p00; s_p[0][64 + lane] = p10; s_p[0][128 + lane] = p20;
    s_p[1][lane] = p01; s_p[1][64 + lane] = p11; s_p[1][128 + lane] = p21;
    s_p[2][lane] = p02; s_p[2][64 + lane] = p12; s_p[2][128 + lane] = p22;
    s_p[3][lane] = p03; s_p[3][64 + lane] = p13; s_p[3][128 + lane] = p23;

    float pz0 = p00 + p10 + p20, pz1 = p01 + p11 + p21;
    float pz2 = p02 + p12 + p22, pz3 = p03 + p13 + p23;
    #pragma unroll
    for (int off = 1; off < 64; off <<= 1) {
      pz0 += __shfl_xor(pz0, off);
      pz1 += __shfl_xor(pz1, off);
      pz2 += __shfl_xor(pz2, off);
      pz3 += __shfl_xor(pz3, off);
    }
    z0 = z0 * sc0 + pz0;
    z1 = z1 * sc1 + pz1;
    z2 = z2 * sc2 + pz2;
    z3 = z3 * sc3 + pz3;

    // PV over this pass
    const float sch = selh(hh, sc0, sc1, sc2, sc3);
    ax *= sch; ay *= sch;
    const float* pr = s_p[hh];
    const int cnt4 = (cnt + 3) & ~3;
    for (int it = 0; it < cnt4; it += 4) {
      const float4 pq = *(const float4*)&pr[it];
      const int4 iq = *(const int4*)&s_idx[pbase + it];
      const float2 v0 = *(const float2*)(vb + (size_t)(iq.x & (NO - 1)) * LAT);
      const float2 v1 = *(const float2*)(vb + (size_t)(iq.y & (NO - 1)) * LAT);
      const float2 v2 = *(const float2*)(vb + (size_t)(iq.z & (NO - 1)) * LAT);
      const float2 v3 = *(const float2*)(vb + (size_t)(iq.w & (NO - 1)) * LAT);
      ax = fmaf(pq.x, v0.x, ax); ay = fmaf(pq.x, v0.y, ay);
      ax = fmaf(pq.y, v1.x, ax); ay = fmaf(pq.y, v1.y, ay);
      ax = fmaf(pq.z, v2.x, ax); ay = fmaf(pq.z, v2.y, ay);
      ax = fmaf(pq.w, v3.x, ax); ay = fmaf(pq.w, v3.y, ay);
    }
  }

  // ---- output: lane owns cols c0, c0+1 ----
  const float zz = selh(hh, z0, z1, z2, z3);
  float2 o2;
  o2.x = (Nv > 0) ? (ax / zz) : 0.0f;
  o2.y = (Nv > 0) ? (ay / zz) : 0.0f;
  *(float2*)&out[(size_t)qg * LAT + c0] = o2;
}

extern "C" void kernel_launch(void* const* d_in, const int* in_sizes, int n_in,
                              void* d_out, int out_size, void* d_ws, size_t ws_size,
                              hipStream_t stream) {
  const float* h_obs     = (const float*)d_in[0];
  const float* pos_obs   = (const float*)d_in[1];
  const float* pos_query = (const float*)d_in[2];
  const int*   obs_mask  = (const int*)d_in[3];
  const float* W1        = (const float*)d_in[4];
  const float* b1        = (const float*)d_in[5];
  const float* W2        = (const float*)d_in[6];
  const float* b2        = (const float*)d_in[7];
  const float* ln_g      = (const float*)d_in[8];
  const float* ln_b      = (const float*)d_in[9];
  const float* Wv        = (const float*)d_in[10];
  const float* bv        = (const float*)d_in[11];
  float* outp = (float*)d_out;
  float* v    = (float*)d_ws;   // 1 MB

  gano_prep_kernel<<<(B_ * NO) / 4, 256, 0, stream>>>(h_obs, ln_g, ln_b, Wv, bv, v);
  gano_main_kernel<<<B_ * NQ, 64, 0, stream>>>(pos_obs, pos_query, obs_mask,
                                               W1, b1, W2, b2, v, outp);
}